// Round 1
// baseline (860.485 us; speedup 1.0000x reference)
//
#include <hip/hip_runtime.h>

// Problem constants
#define B_DIM   4096
#define C_DIM   128
#define TOPK    8
#define K_INST  16
#define P_IDS   256          // B/K_INST
#define N_DIM   32768        // B*TOPK
#define INV_TEMP 20.0f       // 1/0.05
#define EPS 1e-6f

typedef unsigned short u16;
typedef __attribute__((ext_vector_type(8))) short bf16x8;
typedef __attribute__((ext_vector_type(4))) float f32x4;

struct alignas(8) U16x4 { u16 x, y, z, w; };

__device__ __forceinline__ u16 f2bf(float x) {
    union { float f; unsigned u; } v; v.f = x;
    unsigned r = v.u + 0x7fffu + ((v.u >> 16) & 1u);   // RTN-even
    return (u16)(r >> 16);
}

__device__ __forceinline__ void gload_lds16(const u16* g, u16* l) {
    __builtin_amdgcn_global_load_lds(
        (__attribute__((address_space(1))) void*)g,
        (__attribute__((address_space(3))) void*)l,
        16, 0, 0);
}

// ---------------- kernel 1: fp32 -> bf16 convert ----------------
#define NA4 131072           // 4096*128/4
#define NTOT4 1179648        // (4096*128 + 32768*128)/4
__global__ __launch_bounds__(256) void convert_bf16(const float4* __restrict__ fa,
                                                    const float4* __restrict__ fs,
                                                    u16* __restrict__ outA,
                                                    u16* __restrict__ outS) {
    int i = blockIdx.x * 256 + threadIdx.x;
    float4 v;
    u16* dst;
    if (i < NA4) { v = fa[i]; dst = outA + (size_t)i * 4; }
    else         { int j = i - NA4; v = fs[j]; dst = outS + (size_t)j * 4; }
    U16x4 o = { f2bf(v.x), f2bf(v.y), f2bf(v.z), f2bf(v.w) };
    *(U16x4*)dst = o;
}

// ---------------- kernel 2: tiled sim + per-block max/min reduce ----------------
// grid: (256 col-blocks p, 32 row-tiles rt). block=256 (4 waves), 128x128 tile.
__global__ __launch_bounds__(256) void phase1(const u16* __restrict__ A,   // [4096][128] bf16
                                              const u16* __restrict__ Bm,  // [32768][128] bf16
                                              float* __restrict__ blkmax,  // [256][4096]
                                              float* __restrict__ posmin)  // [4096]
{
    __shared__ u16 Als[128 * 32];
    __shared__ u16 Bls[128 * 32];
    __shared__ float smax[2][128];
    __shared__ float smin[2][16];

    const int tid  = threadIdx.x;
    const int lane = tid & 63;
    const int wave = tid >> 6;
    const int wm   = wave >> 1;      // row half (0/1)
    const int wn   = wave & 1;       // col half (0/1)
    const int p    = blockIdx.x;     // identity col-block 0..255
    const int rt   = blockIdx.y;     // row tile 0..31
    const int row0 = rt * 128;
    const int col0 = p * 128;

    f32x4 acc[4][4] = {};

    const int rbase = lane & 15;
    const int koff  = (lane >> 4) * 8;

    for (int kk = 0; kk < 4; ++kk) {
        const int kbase = kk * 32;
        // stage A-tile and B-tile: 512 16B-chunks each, 2 per thread per tile
        {
            int c = tid;
            gload_lds16(A + (size_t)(row0 + (c >> 2)) * C_DIM + kbase + (c & 3) * 8, &Als[c * 8]);
            gload_lds16(Bm + (size_t)(col0 + (c >> 2)) * C_DIM + kbase + (c & 3) * 8, &Bls[c * 8]);
            c = tid + 256;
            gload_lds16(A + (size_t)(row0 + (c >> 2)) * C_DIM + kbase + (c & 3) * 8, &Als[c * 8]);
            gload_lds16(Bm + (size_t)(col0 + (c >> 2)) * C_DIM + kbase + (c & 3) * 8, &Bls[c * 8]);
        }
        __builtin_amdgcn_s_waitcnt(0);
        __syncthreads();

        bf16x8 a[4], b[4];
#pragma unroll
        for (int mi = 0; mi < 4; ++mi)
            a[mi] = *(const bf16x8*)&Als[(wm * 64 + mi * 16 + rbase) * 32 + koff];
#pragma unroll
        for (int ni = 0; ni < 4; ++ni)
            b[ni] = *(const bf16x8*)&Bls[(wn * 64 + ni * 16 + rbase) * 32 + koff];
#pragma unroll
        for (int mi = 0; mi < 4; ++mi)
#pragma unroll
            for (int ni = 0; ni < 4; ++ni)
                acc[mi][ni] = __builtin_amdgcn_mfma_f32_16x16x32_bf16(a[mi], b[ni], acc[mi][ni], 0, 0, 0);
        __syncthreads();
    }

    // ---- epilogue: per-row max over the 128 tile columns ----
    // C/D layout: col = lane&15 (+ni*16+wn*64), row = (lane>>4)*4 + r (+mi*16+wm*64)
    float rmax[4][4];
#pragma unroll
    for (int mi = 0; mi < 4; ++mi)
#pragma unroll
        for (int r = 0; r < 4; ++r) {
            float m = acc[mi][0][r];
            m = fmaxf(m, acc[mi][1][r]);
            m = fmaxf(m, acc[mi][2][r]);
            m = fmaxf(m, acc[mi][3][r]);
            rmax[mi][r] = m;
        }
#pragma unroll
    for (int off = 1; off < 16; off <<= 1)
#pragma unroll
        for (int mi = 0; mi < 4; ++mi)
#pragma unroll
            for (int r = 0; r < 4; ++r)
                rmax[mi][r] = fmaxf(rmax[mi][r], __shfl_xor(rmax[mi][r], off, 64));

    if ((lane & 15) == 0) {
        const int rb = wm * 64 + (lane >> 4) * 4;
#pragma unroll
        for (int mi = 0; mi < 4; ++mi)
#pragma unroll
            for (int r = 0; r < 4; ++r)
                smax[wn][rb + mi * 16 + r] = rmax[mi][r];
    }

    // min only for the diagonal block (rows whose pid == p)
    const bool diag = (rt == (p >> 3));
    const int dloc = p & 7;                  // 16-row group inside the tile
    if (diag && wm == (dloc >> 2)) {
        const int mi = dloc & 3;
        float rmin[4];
#pragma unroll
        for (int r = 0; r < 4; ++r) {
            float m = acc[mi][0][r];
            m = fminf(m, acc[mi][1][r]);
            m = fminf(m, acc[mi][2][r]);
            m = fminf(m, acc[mi][3][r]);
            rmin[r] = m;
        }
#pragma unroll
        for (int off = 1; off < 16; off <<= 1)
#pragma unroll
            for (int r = 0; r < 4; ++r)
                rmin[r] = fminf(rmin[r], __shfl_xor(rmin[r], off, 64));
        if ((lane & 15) == 0) {
#pragma unroll
            for (int r = 0; r < 4; ++r)
                smin[wn][(lane >> 4) * 4 + r] = rmin[r];
        }
    }
    __syncthreads();

    if (tid < 128) {
        float m = fmaxf(smax[0][tid], smax[1][tid]);
        blkmax[(size_t)p * B_DIM + row0 + tid] = m;   // coalesced 128 floats
    }
    if (diag && tid < 16) {
        posmin[p * 16 + tid] = fminf(smin[0][tid], smin[1][tid]);  // global row = p*16+tid
    }
}

// ---------------- kernel 3: per-row loss + mean ----------------
// grid 64 blocks x 256 threads; each block handles 64 rows.
__global__ __launch_bounds__(256) void phase2(const float* __restrict__ blkmax,
                                              const float* __restrict__ posmin,
                                              const int* __restrict__ labels,
                                              float* __restrict__ out) {
    const int tid = threadIdx.x;
    const int bb = tid & 63;
    const int pp = tid >> 6;
    const int b = blockIdx.x * 64 + bb;
    const int pid = labels[b];
    float s = 0.f;
#pragma unroll 4
    for (int p0 = 0; p0 < P_IDS; p0 += 4) {
        const int p = p0 + pp;
        const float v = blkmax[(size_t)p * B_DIM + b];   // coalesced per wave
        s += (p == pid) ? 0.f : __expf(v * INV_TEMP);
    }
    __shared__ float part[4][64];
    part[pp][bb] = s;
    __syncthreads();
    if (tid < 64) {
        const float neg = part[0][tid] + part[1][tid] + part[2][tid] + part[3][tid];
        const float pos = __expf(posmin[blockIdx.x * 64 + tid] * INV_TEMP);
        float loss = -__logf(pos / (pos + neg + EPS) + EPS);
#pragma unroll
        for (int off = 32; off > 0; off >>= 1)
            loss += __shfl_down(loss, off, 64);
        if (tid == 0) atomicAdd(out, loss * (1.0f / (float)B_DIM));
    }
}

extern "C" void kernel_launch(void* const* d_in, const int* in_sizes, int n_in,
                              void* d_out, int out_size, void* d_ws, size_t ws_size,
                              hipStream_t stream) {
    const float* feats   = (const float*)d_in[0];   // [4096,128]
    const float* feats_s = (const float*)d_in[1];   // [4096,8,128]
    const int*   labels  = (const int*)d_in[2];     // [4096]
    float* out = (float*)d_out;

    // workspace layout: bf16 A (1 MB) | bf16 S (8 MB) | blkmax (4 MB) | posmin (16 KB)
    u16* wsA = (u16*)d_ws;
    u16* wsS = wsA + (size_t)B_DIM * C_DIM;
    float* blkmax = (float*)((char*)d_ws + (1u << 20) + (8u << 20));
    float* posmin = blkmax + (size_t)P_IDS * B_DIM;

    hipMemsetAsync(d_out, 0, sizeof(float), stream);
    convert_bf16<<<NTOT4 / 256, 256, 0, stream>>>((const float4*)feats, (const float4*)feats_s, wsA, wsS);
    dim3 g1(P_IDS, B_DIM / 128);
    phase1<<<g1, 256, 0, stream>>>(wsA, wsS, blkmax, posmin);
    phase2<<<B_DIM / 64, 256, 0, stream>>>(blkmax, posmin, labels, out);
}

// Round 2
// 164.767 us; speedup vs baseline: 5.2224x; 5.2224x over previous
//
#include <hip/hip_runtime.h>

// Problem constants
#define B_DIM   4096
#define C_DIM   128
#define TOPK    8
#define K_INST  16
#define P_IDS   256          // B/K_INST
#define N_DIM   32768        // B*TOPK
#define INV_TEMP 20.0f       // 1/0.05
#define EPS 1e-6f

typedef unsigned short u16;
typedef __attribute__((ext_vector_type(8))) short bf16x8;
typedef __attribute__((ext_vector_type(4))) float f32x4;

struct alignas(8) U16x4 { u16 x, y, z, w; };

__device__ __forceinline__ u16 f2bf(float x) {
    union { float f; unsigned u; } v; v.f = x;
    unsigned r = v.u + 0x7fffu + ((v.u >> 16) & 1u);   // RTN-even
    return (u16)(r >> 16);
}

__device__ __forceinline__ void gload_lds16(const u16* g, u16* l) {
    __builtin_amdgcn_global_load_lds(
        (__attribute__((address_space(1))) void*)g,
        (__attribute__((address_space(3))) void*)l,
        16, 0, 0);
}

// ---------------- kernel 1: fp32 -> bf16 convert ----------------
#define NA4 131072           // 4096*128/4
#define NTOT4 1179648        // (4096*128 + 32768*128)/4
__global__ __launch_bounds__(256) void convert_bf16(const float4* __restrict__ fa,
                                                    const float4* __restrict__ fs,
                                                    u16* __restrict__ outA,
                                                    u16* __restrict__ outS) {
    int i = blockIdx.x * 256 + threadIdx.x;
    float4 v;
    u16* dst;
    if (i < NA4) { v = fa[i]; dst = outA + (size_t)i * 4; }
    else         { int j = i - NA4; v = fs[j]; dst = outS + (size_t)j * 4; }
    U16x4 o = { f2bf(v.x), f2bf(v.y), f2bf(v.z), f2bf(v.w) };
    *(U16x4*)dst = o;
}

// ---------------- kernel 2: tiled sim + per-block max/min reduce ----------------
// grid: (256 col-blocks p, 32 row-tiles rt). block=256 (4 waves), 128x128 tile.
__global__ __launch_bounds__(256) void phase1(const u16* __restrict__ A,   // [4096][128] bf16
                                              const u16* __restrict__ Bm,  // [32768][128] bf16
                                              float* __restrict__ blkmax,  // [256][4096]
                                              float* __restrict__ posmin)  // [4096]
{
    __shared__ u16 Als[128 * 32];
    __shared__ u16 Bls[128 * 32];
    __shared__ float smax[2][128];
    __shared__ float smin[2][16];

    const int tid  = threadIdx.x;
    const int lane = tid & 63;
    const int wave = tid >> 6;
    const int wm   = wave >> 1;      // row half (0/1)
    const int wn   = wave & 1;       // col half (0/1)
    const int p    = blockIdx.x;     // identity col-block 0..255
    const int rt   = blockIdx.y;     // row tile 0..31
    const int row0 = rt * 128;
    const int col0 = p * 128;

    f32x4 acc[4][4] = {};

    const int rbase = lane & 15;
    const int koff  = (lane >> 4) * 8;

    for (int kk = 0; kk < 4; ++kk) {
        const int kbase = kk * 32;
        // stage A-tile and B-tile: 512 16B-chunks each, 2 per thread per tile
        {
            int c = tid;
            gload_lds16(A + (size_t)(row0 + (c >> 2)) * C_DIM + kbase + (c & 3) * 8, &Als[c * 8]);
            gload_lds16(Bm + (size_t)(col0 + (c >> 2)) * C_DIM + kbase + (c & 3) * 8, &Bls[c * 8]);
            c = tid + 256;
            gload_lds16(A + (size_t)(row0 + (c >> 2)) * C_DIM + kbase + (c & 3) * 8, &Als[c * 8]);
            gload_lds16(Bm + (size_t)(col0 + (c >> 2)) * C_DIM + kbase + (c & 3) * 8, &Bls[c * 8]);
        }
        __builtin_amdgcn_s_waitcnt(0);
        __syncthreads();

        bf16x8 a[4], b[4];
#pragma unroll
        for (int mi = 0; mi < 4; ++mi)
            a[mi] = *(const bf16x8*)&Als[(wm * 64 + mi * 16 + rbase) * 32 + koff];
#pragma unroll
        for (int ni = 0; ni < 4; ++ni)
            b[ni] = *(const bf16x8*)&Bls[(wn * 64 + ni * 16 + rbase) * 32 + koff];
#pragma unroll
        for (int mi = 0; mi < 4; ++mi)
#pragma unroll
            for (int ni = 0; ni < 4; ++ni)
                acc[mi][ni] = __builtin_amdgcn_mfma_f32_16x16x32_bf16(a[mi], b[ni], acc[mi][ni], 0, 0, 0);
        __syncthreads();
    }

    // ---- epilogue: per-row max over the 128 tile columns ----
    // C/D layout: col = lane&15 (+ni*16+wn*64), row = (lane>>4)*4 + r (+mi*16+wm*64)
    float rmax[4][4];
#pragma unroll
    for (int mi = 0; mi < 4; ++mi)
#pragma unroll
        for (int r = 0; r < 4; ++r) {
            float m = acc[mi][0][r];
            m = fmaxf(m, acc[mi][1][r]);
            m = fmaxf(m, acc[mi][2][r]);
            m = fmaxf(m, acc[mi][3][r]);
            rmax[mi][r] = m;
        }
#pragma unroll
    for (int off = 1; off < 16; off <<= 1)
#pragma unroll
        for (int mi = 0; mi < 4; ++mi)
#pragma unroll
            for (int r = 0; r < 4; ++r)
                rmax[mi][r] = fmaxf(rmax[mi][r], __shfl_xor(rmax[mi][r], off, 64));

    if ((lane & 15) == 0) {
        const int rb = wm * 64 + (lane >> 4) * 4;
#pragma unroll
        for (int mi = 0; mi < 4; ++mi)
#pragma unroll
            for (int r = 0; r < 4; ++r)
                smax[wn][rb + mi * 16 + r] = rmax[mi][r];
    }

    // min only for the diagonal block (rows whose pid == p).
    // NOTE: mi must stay a COMPILE-TIME constant index into acc[][] — a dynamic
    // index (R1: `acc[dloc&3][ni][r]`) demotes the whole accumulator array to
    // scratch -> 4 GB of spill traffic, 775 us. Unroll + uniform guard instead.
    const bool diag = (rt == (p >> 3));
    const int dloc = p & 7;                  // 16-row group inside the tile
    if (diag && wm == (dloc >> 2)) {
        const int misel = dloc & 3;
        float rmin[4];
#pragma unroll
        for (int mi = 0; mi < 4; ++mi) {
            if (mi == misel) {
#pragma unroll
                for (int r = 0; r < 4; ++r) {
                    float m = acc[mi][0][r];
                    m = fminf(m, acc[mi][1][r]);
                    m = fminf(m, acc[mi][2][r]);
                    m = fminf(m, acc[mi][3][r]);
                    rmin[r] = m;
                }
            }
        }
#pragma unroll
        for (int off = 1; off < 16; off <<= 1)
#pragma unroll
            for (int r = 0; r < 4; ++r)
                rmin[r] = fminf(rmin[r], __shfl_xor(rmin[r], off, 64));
        if ((lane & 15) == 0) {
#pragma unroll
            for (int r = 0; r < 4; ++r)
                smin[wn][(lane >> 4) * 4 + r] = rmin[r];
        }
    }
    __syncthreads();

    if (tid < 128) {
        float m = fmaxf(smax[0][tid], smax[1][tid]);
        blkmax[(size_t)p * B_DIM + row0 + tid] = m;   // coalesced 128 floats
    }
    if (diag && tid < 16) {
        posmin[p * 16 + tid] = fminf(smin[0][tid], smin[1][tid]);  // global row = p*16+tid
    }
}

// ---------------- kernel 3: per-row loss + mean ----------------
// grid 64 blocks x 256 threads; each block handles 64 rows.
__global__ __launch_bounds__(256) void phase2(const float* __restrict__ blkmax,
                                              const float* __restrict__ posmin,
                                              const int* __restrict__ labels,
                                              float* __restrict__ out) {
    const int tid = threadIdx.x;
    const int bb = tid & 63;
    const int pp = tid >> 6;
    const int b = blockIdx.x * 64 + bb;
    const int pid = labels[b];
    float s = 0.f;
#pragma unroll 4
    for (int p0 = 0; p0 < P_IDS; p0 += 4) {
        const int p = p0 + pp;
        const float v = blkmax[(size_t)p * B_DIM + b];   // coalesced per wave
        s += (p == pid) ? 0.f : __expf(v * INV_TEMP);
    }
    __shared__ float part[4][64];
    part[pp][bb] = s;
    __syncthreads();
    if (tid < 64) {
        const float neg = part[0][tid] + part[1][tid] + part[2][tid] + part[3][tid];
        const float pos = __expf(posmin[blockIdx.x * 64 + tid] * INV_TEMP);
        float loss = -__logf(pos / (pos + neg + EPS) + EPS);
#pragma unroll
        for (int off = 32; off > 0; off >>= 1)
            loss += __shfl_down(loss, off, 64);
        if (tid == 0) atomicAdd(out, loss * (1.0f / (float)B_DIM));
    }
}

extern "C" void kernel_launch(void* const* d_in, const int* in_sizes, int n_in,
                              void* d_out, int out_size, void* d_ws, size_t ws_size,
                              hipStream_t stream) {
    const float* feats   = (const float*)d_in[0];   // [4096,128]
    const float* feats_s = (const float*)d_in[1];   // [4096,8,128]
    const int*   labels  = (const int*)d_in[2];     // [4096]
    float* out = (float*)d_out;

    // workspace layout: bf16 A (1 MB) | bf16 S (8 MB) | blkmax (4 MB) | posmin (16 KB)
    u16* wsA = (u16*)d_ws;
    u16* wsS = wsA + (size_t)B_DIM * C_DIM;
    float* blkmax = (float*)((char*)d_ws + (1u << 20) + (8u << 20));
    float* posmin = blkmax + (size_t)P_IDS * B_DIM;

    hipMemsetAsync(d_out, 0, sizeof(float), stream);
    convert_bf16<<<NTOT4 / 256, 256, 0, stream>>>((const float4*)feats, (const float4*)feats_s, wsA, wsS);
    dim3 g1(P_IDS, B_DIM / 128);
    phase1<<<g1, 256, 0, stream>>>(wsA, wsS, blkmax, posmin);
    phase2<<<B_DIM / 64, 256, 0, stream>>>(blkmax, posmin, labels, out);
}

// Round 3
// 153.120 us; speedup vs baseline: 5.6197x; 1.0761x over previous
//
#include <hip/hip_runtime.h>

// Problem constants
#define B_DIM   4096
#define C_DIM   128
#define TOPK    8
#define K_INST  16
#define P_IDS   256          // B/K_INST
#define N_DIM   32768        // B*TOPK
#define INV_TEMP 20.0f       // 1/0.05
#define EPS 1e-6f

typedef unsigned short u16;
typedef __attribute__((ext_vector_type(8))) short bf16x8;
typedef __attribute__((ext_vector_type(4))) float f32x4;

struct alignas(8) U16x4 { u16 x, y, z, w; };

__device__ __forceinline__ u16 f2bf(float x) {
    union { float f; unsigned u; } v; v.f = x;
    unsigned r = v.u + 0x7fffu + ((v.u >> 16) & 1u);   // RTN-even
    return (u16)(r >> 16);
}

__device__ __forceinline__ void gload_lds16(const u16* g, u16* l) {
    __builtin_amdgcn_global_load_lds(
        (__attribute__((address_space(1))) void*)g,
        (__attribute__((address_space(3))) void*)l,
        16, 0, 0);
}

// ---------------- kernel 1: fp32 -> bf16 convert ----------------
#define NA4 131072           // 4096*128/4
#define NTOT4 1179648        // (4096*128 + 32768*128)/4
__global__ __launch_bounds__(256) void convert_bf16(const float4* __restrict__ fa,
                                                    const float4* __restrict__ fs,
                                                    u16* __restrict__ outA,
                                                    u16* __restrict__ outS) {
    int i = blockIdx.x * 256 + threadIdx.x;
    float4 v;
    u16* dst;
    if (i < NA4) { v = fa[i]; dst = outA + (size_t)i * 4; }
    else         { int j = i - NA4; v = fs[j]; dst = outS + (size_t)j * 4; }
    U16x4 o = { f2bf(v.x), f2bf(v.y), f2bf(v.z), f2bf(v.w) };
    *(U16x4*)dst = o;
}

// ---------------- kernel 2: tiled sim + per-block max/min reduce ----------------
// grid: (256 col-blocks p, 32 row-tiles rt). block=256 (4 waves), 128x128 tile.
// Single-shot K=128: B tile staged ONCE into LDS (XOR-swizzled), A fragments
// loaded directly from global (L1/L2-hot, 64B-line coalesced), ONE barrier.
__global__ __launch_bounds__(256, 3) void phase1(const u16* __restrict__ A,   // [4096][128] bf16
                                                 const u16* __restrict__ Bm,  // [32768][128] bf16
                                                 float* __restrict__ blkmax,  // [256][4096]
                                                 float* __restrict__ posmin)  // [4096]
{
    // Swizzled B tile: 16B chunk (n, kc) lives at slot n*16 + (kc ^ (n&7)).
    // Swizzle is realized by permuting the GLOBAL source address per lane,
    // since global_load_lds forces LDS dst = base + lane*16 (contiguous).
    __shared__ u16 Bls[128 * 128];          // 32 KB
    __shared__ float smax[2][128];
    __shared__ float smin[2][16];

    const int tid  = threadIdx.x;
    const int lane = tid & 63;
    const int wave = tid >> 6;
    const int wm   = wave >> 1;      // row half (0/1)
    const int wn   = wave & 1;       // col half (0/1)
    const int p    = blockIdx.x;     // identity col-block 0..255
    const int rt   = blockIdx.y;     // row tile 0..31
    const int row0 = rt * 128;
    const int col0 = p * 128;

    // ---- stage B (whole 128x128 tile, 2048 chunks, 8 per thread) ----
    // slot c = tid + 256*t: n = c>>4 = (tid>>4)+16t, kc = (c&15)^((c>>4)&7)
    // (kc is constant across t since 16t = 0 mod 8 in (c>>4)&7)
    {
        const int n0 = tid >> 4;
        const int kc = (tid & 15) ^ ((tid >> 4) & 7);
        const u16* src = Bm + (size_t)(col0 + n0) * C_DIM + kc * 8;
        u16* dst = &Bls[(size_t)tid * 8];
#pragma unroll
        for (int t = 0; t < 8; ++t)
            gload_lds16(src + t * 16 * C_DIM, dst + t * 256 * 8);
    }

    // ---- A fragments straight from global (issued before the barrier) ----
    // a[mi][kk]: A[row0 + wm*64 + mi*16 + (lane&15)][kk*32 + (lane>>4)*8 ..+7]
    const int r = lane & 15;
    const int g = lane >> 4;
    bf16x8 a[4][4];
    {
        const u16* arow = A + (size_t)(row0 + wm * 64 + r) * C_DIM + g * 8;
#pragma unroll
        for (int mi = 0; mi < 4; ++mi)
#pragma unroll
            for (int kk = 0; kk < 4; ++kk)
                a[mi][kk] = *(const bf16x8*)(arow + (size_t)mi * 16 * C_DIM + kk * 32);
    }

    __builtin_amdgcn_s_waitcnt(0);
    __syncthreads();

    // ---- MFMA main loop: 4 k-steps x 16 MFMAs, no further barriers ----
    f32x4 acc[4][4] = {};
    const int x = lane & 7;          // = (n&7) of this lane's fragment rows
#pragma unroll
    for (int kk = 0; kk < 4; ++kk) {
        bf16x8 b[4];
#pragma unroll
        for (int ni = 0; ni < 4; ++ni) {
            const int n = wn * 64 + ni * 16 + r;
            const int slot = n * 16 + (((kk * 4 + g) ^ x));
            b[ni] = *(const bf16x8*)&Bls[slot * 8];
        }
#pragma unroll
        for (int mi = 0; mi < 4; ++mi)
#pragma unroll
            for (int ni = 0; ni < 4; ++ni)
                acc[mi][ni] = __builtin_amdgcn_mfma_f32_16x16x32_bf16(a[mi][kk], b[ni], acc[mi][ni], 0, 0, 0);
    }

    // ---- epilogue: per-row max over the 128 tile columns ----
    // C/D layout: col = lane&15 (+ni*16+wn*64), row = (lane>>4)*4 + reg (+mi*16+wm*64)
    float rmax[4][4];
#pragma unroll
    for (int mi = 0; mi < 4; ++mi)
#pragma unroll
        for (int rr = 0; rr < 4; ++rr) {
            float m = acc[mi][0][rr];
            m = fmaxf(m, acc[mi][1][rr]);
            m = fmaxf(m, acc[mi][2][rr]);
            m = fmaxf(m, acc[mi][3][rr]);
            rmax[mi][rr] = m;
        }
#pragma unroll
    for (int off = 1; off < 16; off <<= 1)
#pragma unroll
        for (int mi = 0; mi < 4; ++mi)
#pragma unroll
            for (int rr = 0; rr < 4; ++rr)
                rmax[mi][rr] = fmaxf(rmax[mi][rr], __shfl_xor(rmax[mi][rr], off, 64));

    if ((lane & 15) == 0) {
        const int rb = wm * 64 + (lane >> 4) * 4;
#pragma unroll
        for (int mi = 0; mi < 4; ++mi)
#pragma unroll
            for (int rr = 0; rr < 4; ++rr)
                smax[wn][rb + mi * 16 + rr] = rmax[mi][rr];
    }

    // min only for the diagonal block (rows whose pid == p).
    // NOTE: mi must stay a COMPILE-TIME index into acc[][] — dynamic indexing
    // demotes the accumulators to scratch (R1: 4 GB spill, 775 us).
    const bool diag = (rt == (p >> 3));
    const int dloc = p & 7;                  // 16-row group inside the tile
    if (diag && wm == (dloc >> 2)) {
        const int misel = dloc & 3;
        float rmin[4];
#pragma unroll
        for (int mi = 0; mi < 4; ++mi) {
            if (mi == misel) {
#pragma unroll
                for (int rr = 0; rr < 4; ++rr) {
                    float m = acc[mi][0][rr];
                    m = fminf(m, acc[mi][1][rr]);
                    m = fminf(m, acc[mi][2][rr]);
                    m = fminf(m, acc[mi][3][rr]);
                    rmin[rr] = m;
                }
            }
        }
#pragma unroll
        for (int off = 1; off < 16; off <<= 1)
#pragma unroll
            for (int rr = 0; rr < 4; ++rr)
                rmin[rr] = fminf(rmin[rr], __shfl_xor(rmin[rr], off, 64));
        if ((lane & 15) == 0) {
#pragma unroll
            for (int rr = 0; rr < 4; ++rr)
                smin[wn][(lane >> 4) * 4 + rr] = rmin[rr];
        }
    }
    __syncthreads();

    if (tid < 128) {
        float m = fmaxf(smax[0][tid], smax[1][tid]);
        blkmax[(size_t)p * B_DIM + row0 + tid] = m;   // coalesced 128 floats
    }
    if (diag && tid < 16) {
        posmin[p * 16 + tid] = fminf(smin[0][tid], smin[1][tid]);  // global row = p*16+tid
    }
}

// ---------------- kernel 3: per-row loss + mean ----------------
// grid 256 blocks x 256 threads; each block handles 16 rows, 16 p-slices.
__global__ __launch_bounds__(256) void phase2(const float* __restrict__ blkmax,
                                              const float* __restrict__ posmin,
                                              const int* __restrict__ labels,
                                              float* __restrict__ out) {
    const int tid = threadIdx.x;
    const int rr = tid & 15;          // row within this block's 16
    const int slice = tid >> 4;       // p-slice 0..15
    const int b = blockIdx.x * 16 + rr;
    const int pid = labels[b];
    float s = 0.f;
#pragma unroll
    for (int j = 0; j < 16; ++j) {
        const int pp = slice * 16 + j;
        const float v = blkmax[(size_t)pp * B_DIM + b];
        s += (pp == pid) ? 0.f : __expf(v * INV_TEMP);
    }
    __shared__ float part[16][17];
    part[slice][rr] = s;
    __syncthreads();
    if (tid < 16) {
        float neg = 0.f;
#pragma unroll
        for (int j = 0; j < 16; ++j) neg += part[j][tid];
        const float pos = __expf(posmin[blockIdx.x * 16 + tid] * INV_TEMP);
        float loss = -__logf(pos / (pos + neg + EPS) + EPS);
#pragma unroll
        for (int off = 8; off > 0; off >>= 1)
            loss += __shfl_down(loss, off, 64);
        if (tid == 0) atomicAdd(out, loss * (1.0f / (float)B_DIM));
    }
}

extern "C" void kernel_launch(void* const* d_in, const int* in_sizes, int n_in,
                              void* d_out, int out_size, void* d_ws, size_t ws_size,
                              hipStream_t stream) {
    const float* feats   = (const float*)d_in[0];   // [4096,128]
    const float* feats_s = (const float*)d_in[1];   // [4096,8,128]
    const int*   labels  = (const int*)d_in[2];     // [4096]
    float* out = (float*)d_out;

    // workspace layout: bf16 A (1 MB) | bf16 S (8 MB) | blkmax (4 MB) | posmin (16 KB)
    u16* wsA = (u16*)d_ws;
    u16* wsS = wsA + (size_t)B_DIM * C_DIM;
    float* blkmax = (float*)((char*)d_ws + (1u << 20) + (8u << 20));
    float* posmin = blkmax + (size_t)P_IDS * B_DIM;

    hipMemsetAsync(d_out, 0, sizeof(float), stream);
    convert_bf16<<<NTOT4 / 256, 256, 0, stream>>>((const float4*)feats, (const float4*)feats_s, wsA, wsS);
    dim3 g1(P_IDS, B_DIM / 128);
    phase1<<<g1, 256, 0, stream>>>(wsA, wsS, blkmax, posmin);
    phase2<<<B_DIM / 16, 256, 0, stream>>>(blkmax, posmin, labels, out);
}